// Round 14
// baseline (250.109 us; speedup 1.0000x reference)
//
#include <hip/hip_runtime.h>
#include <hip/hip_bf16.h>

// Edgedropping: per-edge MLP score -> sigmoid -> global min/max normalize ->
// mask -> stable stream compaction of edge_index (2 rows) + edge_weight (14 rows).
// Output buffer: float32.
// R14 = R13 (proven 184us) with exactly ONE change: k_scan launch removed;
// k_scatter wave 1 self-computes its exclusive prefix from counts[] (L2-resident
// 4KB, int add = order-independent) while wave 0 scans the 64 in-block counts.
// Pass 1 / pass 2 (high-MLP write loop) byte-identical to R13.

constexpr int BLOCK = 256;
constexpr int CHUNK = 4096;            // edges per count/scatter chunk
constexpr int ROUNDS = CHUNK / BLOCK;  // 16

__device__ __forceinline__ bool mask_of(float s, float vmin, float range) {
    float t = __fdiv_rn(__fsub_rn(s, vmin), range);
    float sn = __fadd_rn(__fmul_rn(t, 1.2f), -0.1f);
    return sn > 0.0f;
}

// ---- kernels ---------------------------------------------------------------

__global__ void k_compute_s(const float* __restrict__ ew,
                            const float* __restrict__ W1, const float* __restrict__ b1,
                            const float* __restrict__ W2, const float* __restrict__ b2,
                            const float* __restrict__ rl,
                            float* __restrict__ s_out,
                            float2* __restrict__ partial,
                            long long E) {
    __shared__ double sW1d[98], sW2d[7];
    __shared__ float sb1[7];
    __shared__ float sb2, srl;
    int tid = threadIdx.x;
    if (tid < 98) sW1d[tid] = (double)W1[tid];
    if (tid < 7) { sW2d[tid] = (double)W2[tid]; sb1[tid] = b1[tid]; }
    if (tid == 0) { sb2 = b2[0]; srl = rl[0]; }
    __syncthreads();

    long long e = (long long)blockIdx.x * BLOCK + tid;
    float lmin = __uint_as_float(0x7F800000u), lmax = 0.0f;

    if (e < E) {
        const float2* p2 = (const float2*)ew + e * 7;   // e*56 B, 8B-aligned
        float2 q0 = p2[0], q1 = p2[1], q2 = p2[2], q3 = p2[3],
               q4 = p2[4], q5 = p2[5], q6 = p2[6];
        float w[14] = {q0.x, q0.y, q1.x, q1.y, q2.x, q2.y, q3.x, q3.y,
                       q4.x, q4.y, q5.x, q5.y, q6.x, q6.y};

        // layer 1: 7 f64 dots, j-outer (per-k accumulation order matches R3 pass)
        double a0 = 0.0, a1 = 0.0, a2 = 0.0, a3 = 0.0, a4 = 0.0, a5 = 0.0, a6 = 0.0;
#pragma unroll
        for (int j = 0; j < 14; ++j) {
            double fd = (double)w[j];
            a0 += fd * sW1d[0 * 14 + j];
            a1 += fd * sW1d[1 * 14 + j];
            a2 += fd * sW1d[2 * 14 + j];
            a3 += fd * sW1d[3 * 14 + j];
            a4 += fd * sW1d[4 * 14 + j];
            a5 += fd * sW1d[5 * 14 + j];
            a6 += fd * sW1d[6 * 14 + j];
        }
        // layer 2 (same rounding points as passed versions)
        double acc2 = 0.0;
#define L2STEP(kk, ak) { float hp = __fadd_rn((float)(ak), sb1[kk]); \
                         hp = fmaxf(hp, 0.0f); \
                         acc2 += (double)hp * sW2d[kk]; }
        L2STEP(0, a0) L2STEP(1, a1) L2STEP(2, a2) L2STEP(3, a3)
        L2STEP(4, a4) L2STEP(5, a5) L2STEP(6, a6)
#undef L2STEP
        float raw = __fadd_rn((float)acc2, sb2);
        float z = __fdiv_rn(__fadd_rn(srl, raw), 0.05f);
        float s = __fdiv_rn(1.0f, __fadd_rn(1.0f, expf(-z)));
        s_out[e] = s;
        lmin = s;
        lmax = s;
    }
#pragma unroll
    for (int off = 32; off; off >>= 1) {
        lmin = fminf(lmin, __shfl_down(lmin, off));
        lmax = fmaxf(lmax, __shfl_down(lmax, off));
    }
    __shared__ float wmn[4], wmx[4];
    int lane = tid & 63, wid = tid >> 6;
    if (lane == 0) { wmn[wid] = lmin; wmx[wid] = lmax; }
    __syncthreads();
    if (tid == 0) {
        float m0 = wmn[0], M0 = wmx[0];
#pragma unroll
        for (int q = 1; q < 4; ++q) { m0 = fminf(m0, wmn[q]); M0 = fmaxf(M0, wmx[q]); }
        float2 pr; pr.x = m0; pr.y = M0;
        partial[blockIdx.x] = pr;
    }
}

// single block: reduce per-block partials -> mm[0]=vmin, mm[1]=vmax
__global__ void k_minmax(const float2* __restrict__ partial, int n,
                         float* __restrict__ mm) {
    int tid = threadIdx.x;
    float lmin = __uint_as_float(0x7F800000u), lmax = 0.0f;
    for (int i = tid; i < n; i += 1024) {
        float2 p = partial[i];
        lmin = fminf(lmin, p.x);
        lmax = fmaxf(lmax, p.y);
    }
#pragma unroll
    for (int off = 32; off; off >>= 1) {
        lmin = fminf(lmin, __shfl_down(lmin, off));
        lmax = fmaxf(lmax, __shfl_down(lmax, off));
    }
    __shared__ float wmn[16], wmx[16];
    int lane = tid & 63, wid = tid >> 6;
    if (lane == 0) { wmn[wid] = lmin; wmx[wid] = lmax; }
    __syncthreads();
    if (tid == 0) {
        float m = wmn[0], M = wmx[0];
#pragma unroll
        for (int q = 1; q < 16; ++q) { m = fminf(m, wmn[q]); M = fmaxf(M, wmx[q]); }
        mm[0] = m; mm[1] = M;
    }
}

__global__ void k_count(const float* __restrict__ s_arr,
                        const float* __restrict__ mm,
                        int* __restrict__ counts, long long E) {
    int chunk = blockIdx.x;
    long long base = (long long)chunk * CHUNK;
    float vmin = mm[0];
    float range = __fsub_rn(mm[1], vmin);
    int tid = threadIdx.x;
    int cnt = 0;
#pragma unroll
    for (int r = 0; r < ROUNDS; ++r) {
        long long e = base + r * BLOCK + tid;
        if (e < E) cnt += mask_of(s_arr[e], vmin, range) ? 1 : 0;
    }
#pragma unroll
    for (int off = 32; off; off >>= 1) cnt += __shfl_down(cnt, off);
    __shared__ int wc[4];
    if ((tid & 63) == 0) wc[tid >> 6] = cnt;
    __syncthreads();
    if (tid == 0) counts[chunk] = wc[0] + wc[1] + wc[2] + wc[3];
}

__global__ void k_scatter(const float* __restrict__ s_arr,
                          const float* __restrict__ mm,
                          const int* __restrict__ counts,
                          const int* __restrict__ ei,
                          const float* __restrict__ ew,
                          float* __restrict__ out,
                          long long E, int K) {
    int chunk = blockIdx.x;
    long long base = (long long)chunk * CHUNK;
    int tid = threadIdx.x, lane = tid & 63, wid = tid >> 6;
    float vmin = mm[0];
    float range = __fsub_rn(mm[1], vmin);

    __shared__ int cnt_rw[64];   // [round*4 + wave]
    __shared__ int off_rw[64];
    __shared__ int base_s;

    // pass 1: per-(round,wave) mask counts (identical to R13)
    for (int r = 0; r < ROUNDS; ++r) {
        long long e = base + r * BLOCK + tid;
        bool m = (e < E) && mask_of(s_arr[e], vmin, range);
        unsigned long long bal = __ballot(m);
        if (lane == 0) cnt_rw[r * 4 + wid] = (int)__popcll(bal);
    }
    __syncthreads();
    // wave 0: exclusive scan of the 64 in-block counts
    if (tid < 64) {
        int v = cnt_rw[tid];
        int x = v;
#pragma unroll
        for (int off = 1; off < 64; off <<= 1) {
            int y = __shfl_up(x, off);
            if (lane >= off) x += y;
        }
        off_rw[tid] = x - v;   // exclusive
    }
    // wave 1 (concurrent): exclusive global prefix = sum of counts[0..chunk)
    if (wid == 1) {
        int sum = 0;
        for (int i = lane; i < chunk; i += 64) sum += counts[i];
#pragma unroll
        for (int off = 32; off; off >>= 1) sum += __shfl_xor(sum, off);
        if (lane == 0) base_s = sum;
    }
    __syncthreads();

    int chunk_base = base_s;
    unsigned long long lt = (lane == 0) ? 0ull : ((1ull << lane) - 1ull);

    // pass 2: write (byte-identical to R13)
    for (int r = 0; r < ROUNDS; ++r) {
        long long e = base + r * BLOCK + tid;
        bool m = (e < E) && mask_of(s_arr[e], vmin, range);
        unsigned long long bal = __ballot(m);
        int myrank = __popcll(bal & lt);
        if (m) {
            long long posl = (long long)chunk_base + off_rw[r * 4 + wid] + myrank;
            if (posl >= 0 && posl < (long long)K) {
                size_t pos = (size_t)posl;
                size_t Ks = (size_t)K;
                out[pos]      = (float)ei[e];
                out[Ks + pos] = (float)ei[E + e];
#pragma unroll
                for (int rr = 0; rr < 14; ++rr)
                    out[(size_t)(2 + rr) * Ks + pos] = ew[(size_t)rr * E + e];
            }
        }
    }
}

// ---- launch ----------------------------------------------------------------

extern "C" void kernel_launch(void* const* d_in, const int* in_sizes, int n_in,
                              void* d_out, int out_size, void* d_ws, size_t ws_size,
                              hipStream_t stream) {
    const int*   ei = (const int*)d_in[1];
    const float* ew = (const float*)d_in[2];
    const float* W1 = (const float*)d_in[3];
    const float* b1 = (const float*)d_in[4];
    const float* W2 = (const float*)d_in[5];
    const float* b2 = (const float*)d_in[6];
    const float* rl = (const float*)d_in[7];

    long long E = (long long)in_sizes[2] / 14;
    int K = out_size / 16;
    int nchunks = (int)((E + CHUNK - 1) / CHUNK);
    int nblocks = (int)((E + BLOCK - 1) / BLOCK);

    // ws: s_arr E*4 | partial nblocks*8 | mm 8B | counts
    char* ws = (char*)d_ws;
    float*  s_arr   = (float*)ws;
    float2* partial = (float2*)(ws + (size_t)E * 4);
    float*  mm      = (float*)(ws + (size_t)E * 4 + (size_t)nblocks * 8);
    int*    counts  = (int*)(ws + (size_t)E * 4 + (size_t)nblocks * 8 + 8);

    float* out = (float*)d_out;

    k_compute_s<<<nblocks, BLOCK, 0, stream>>>(ew, W1, b1, W2, b2, rl,
                                               s_arr, partial, E);
    k_minmax<<<1, 1024, 0, stream>>>(partial, nblocks, mm);
    k_count<<<nchunks, BLOCK, 0, stream>>>(s_arr, mm, counts, E);
    k_scatter<<<nchunks, BLOCK, 0, stream>>>(s_arr, mm, counts, ei, ew, out, E, K);
}

// Round 15
// 184.751 us; speedup vs baseline: 1.3538x; 1.3538x over previous
//
#include <hip/hip_runtime.h>
#include <hip/hip_bf16.h>

// Edgedropping: per-edge MLP score -> sigmoid -> global min/max normalize ->
// mask -> stable stream compaction of edge_index (2 rows) + edge_weight (14 rows).
// Output buffer: float32.
// R15 = byte-exact revert to R13/R9 (proven 184us, 3x).
// Final ledger: compute_s must stay 1-edge/thread (64-VGPR pin; 2-edge spills ~1GB);
// scatter must stay per-round high-MLP with precomputed offsets[] (dedicated k_scan):
//   lookback +74us, ballot-cache+self-prefix +55us, row-major +56us, self-prefix +66us.

constexpr int BLOCK = 256;
constexpr int CHUNK = 4096;            // edges per count/scatter chunk
constexpr int ROUNDS = CHUNK / BLOCK;  // 16

__device__ __forceinline__ bool mask_of(float s, float vmin, float range) {
    float t = __fdiv_rn(__fsub_rn(s, vmin), range);
    float sn = __fadd_rn(__fmul_rn(t, 1.2f), -0.1f);
    return sn > 0.0f;
}

// ---- kernels ---------------------------------------------------------------

__global__ void k_compute_s(const float* __restrict__ ew,
                            const float* __restrict__ W1, const float* __restrict__ b1,
                            const float* __restrict__ W2, const float* __restrict__ b2,
                            const float* __restrict__ rl,
                            float* __restrict__ s_out,
                            float2* __restrict__ partial,
                            long long E) {
    __shared__ double sW1d[98], sW2d[7];
    __shared__ float sb1[7];
    __shared__ float sb2, srl;
    int tid = threadIdx.x;
    if (tid < 98) sW1d[tid] = (double)W1[tid];
    if (tid < 7) { sW2d[tid] = (double)W2[tid]; sb1[tid] = b1[tid]; }
    if (tid == 0) { sb2 = b2[0]; srl = rl[0]; }
    __syncthreads();

    long long e = (long long)blockIdx.x * BLOCK + tid;
    float lmin = __uint_as_float(0x7F800000u), lmax = 0.0f;

    if (e < E) {
        const float2* p2 = (const float2*)ew + e * 7;   // e*56 B, 8B-aligned
        float2 q0 = p2[0], q1 = p2[1], q2 = p2[2], q3 = p2[3],
               q4 = p2[4], q5 = p2[5], q6 = p2[6];
        float w[14] = {q0.x, q0.y, q1.x, q1.y, q2.x, q2.y, q3.x, q3.y,
                       q4.x, q4.y, q5.x, q5.y, q6.x, q6.y};

        // layer 1: 7 f64 dots, j-outer (per-k accumulation order matches R3 pass)
        double a0 = 0.0, a1 = 0.0, a2 = 0.0, a3 = 0.0, a4 = 0.0, a5 = 0.0, a6 = 0.0;
#pragma unroll
        for (int j = 0; j < 14; ++j) {
            double fd = (double)w[j];
            a0 += fd * sW1d[0 * 14 + j];
            a1 += fd * sW1d[1 * 14 + j];
            a2 += fd * sW1d[2 * 14 + j];
            a3 += fd * sW1d[3 * 14 + j];
            a4 += fd * sW1d[4 * 14 + j];
            a5 += fd * sW1d[5 * 14 + j];
            a6 += fd * sW1d[6 * 14 + j];
        }
        // layer 2 (same rounding points as passed versions)
        double acc2 = 0.0;
#define L2STEP(kk, ak) { float hp = __fadd_rn((float)(ak), sb1[kk]); \
                         hp = fmaxf(hp, 0.0f); \
                         acc2 += (double)hp * sW2d[kk]; }
        L2STEP(0, a0) L2STEP(1, a1) L2STEP(2, a2) L2STEP(3, a3)
        L2STEP(4, a4) L2STEP(5, a5) L2STEP(6, a6)
#undef L2STEP
        float raw = __fadd_rn((float)acc2, sb2);
        float z = __fdiv_rn(__fadd_rn(srl, raw), 0.05f);
        float s = __fdiv_rn(1.0f, __fadd_rn(1.0f, expf(-z)));
        s_out[e] = s;
        lmin = s;
        lmax = s;
    }
#pragma unroll
    for (int off = 32; off; off >>= 1) {
        lmin = fminf(lmin, __shfl_down(lmin, off));
        lmax = fmaxf(lmax, __shfl_down(lmax, off));
    }
    __shared__ float wmn[4], wmx[4];
    int lane = tid & 63, wid = tid >> 6;
    if (lane == 0) { wmn[wid] = lmin; wmx[wid] = lmax; }
    __syncthreads();
    if (tid == 0) {
        float m0 = wmn[0], M0 = wmx[0];
#pragma unroll
        for (int q = 1; q < 4; ++q) { m0 = fminf(m0, wmn[q]); M0 = fmaxf(M0, wmx[q]); }
        float2 pr; pr.x = m0; pr.y = M0;
        partial[blockIdx.x] = pr;
    }
}

// single block: reduce per-block partials -> mm[0]=vmin, mm[1]=vmax
__global__ void k_minmax(const float2* __restrict__ partial, int n,
                         float* __restrict__ mm) {
    int tid = threadIdx.x;
    float lmin = __uint_as_float(0x7F800000u), lmax = 0.0f;
    for (int i = tid; i < n; i += 1024) {
        float2 p = partial[i];
        lmin = fminf(lmin, p.x);
        lmax = fmaxf(lmax, p.y);
    }
#pragma unroll
    for (int off = 32; off; off >>= 1) {
        lmin = fminf(lmin, __shfl_down(lmin, off));
        lmax = fmaxf(lmax, __shfl_down(lmax, off));
    }
    __shared__ float wmn[16], wmx[16];
    int lane = tid & 63, wid = tid >> 6;
    if (lane == 0) { wmn[wid] = lmin; wmx[wid] = lmax; }
    __syncthreads();
    if (tid == 0) {
        float m = wmn[0], M = wmx[0];
#pragma unroll
        for (int q = 1; q < 16; ++q) { m = fminf(m, wmn[q]); M = fmaxf(M, wmx[q]); }
        mm[0] = m; mm[1] = M;
    }
}

__global__ void k_count(const float* __restrict__ s_arr,
                        const float* __restrict__ mm,
                        int* __restrict__ counts, long long E) {
    int chunk = blockIdx.x;
    long long base = (long long)chunk * CHUNK;
    float vmin = mm[0];
    float range = __fsub_rn(mm[1], vmin);
    int tid = threadIdx.x;
    int cnt = 0;
#pragma unroll
    for (int r = 0; r < ROUNDS; ++r) {
        long long e = base + r * BLOCK + tid;
        if (e < E) cnt += mask_of(s_arr[e], vmin, range) ? 1 : 0;
    }
#pragma unroll
    for (int off = 32; off; off >>= 1) cnt += __shfl_down(cnt, off);
    __shared__ int wc[4];
    if ((tid & 63) == 0) wc[tid >> 6] = cnt;
    __syncthreads();
    if (tid == 0) counts[chunk] = wc[0] + wc[1] + wc[2] + wc[3];
}

// single block, 1024 threads, LDS Hillis-Steele; requires nchunks <= 1024
__global__ void k_scan(const int* __restrict__ counts, int* __restrict__ offsets,
                       int nchunks) {
    __shared__ int tmp[1024];
    int tid = threadIdx.x;
    int v = (tid < nchunks) ? counts[tid] : 0;
    tmp[tid] = v;
    for (int off = 1; off < 1024; off <<= 1) {
        __syncthreads();
        int y = (tid >= off) ? tmp[tid - off] : 0;
        __syncthreads();
        tmp[tid] += y;
    }
    if (tid < nchunks) offsets[tid] = tmp[tid] - v;   // exclusive prefix
}

__global__ void k_scatter(const float* __restrict__ s_arr,
                          const float* __restrict__ mm,
                          const int* __restrict__ offsets,
                          const int* __restrict__ ei,
                          const float* __restrict__ ew,
                          float* __restrict__ out,
                          long long E, int K) {
    int chunk = blockIdx.x;
    long long base = (long long)chunk * CHUNK;
    int tid = threadIdx.x, lane = tid & 63, wid = tid >> 6;
    float vmin = mm[0];
    float range = __fsub_rn(mm[1], vmin);

    __shared__ int cnt_rw[64];   // [round*4 + wave]
    __shared__ int off_rw[64];

    // pass 1: per-(round,wave) mask counts
    for (int r = 0; r < ROUNDS; ++r) {
        long long e = base + r * BLOCK + tid;
        bool m = (e < E) && mask_of(s_arr[e], vmin, range);
        unsigned long long bal = __ballot(m);
        if (lane == 0) cnt_rw[r * 4 + wid] = (int)__popcll(bal);
    }
    __syncthreads();
    // wave-parallel exclusive scan of the 64 counts (first wave only)
    if (tid < 64) {
        int v = cnt_rw[tid];
        int x = v;
#pragma unroll
        for (int off = 1; off < 64; off <<= 1) {
            int y = __shfl_up(x, off);
            if (lane >= off) x += y;
        }
        off_rw[tid] = x - v;   // exclusive
    }
    __syncthreads();

    int chunk_base = offsets[chunk];
    unsigned long long lt = (lane == 0) ? 0ull : ((1ull << lane) - 1ull);

    // pass 2: write
    for (int r = 0; r < ROUNDS; ++r) {
        long long e = base + r * BLOCK + tid;
        bool m = (e < E) && mask_of(s_arr[e], vmin, range);
        unsigned long long bal = __ballot(m);
        int myrank = __popcll(bal & lt);
        if (m) {
            long long posl = (long long)chunk_base + off_rw[r * 4 + wid] + myrank;
            if (posl >= 0 && posl < (long long)K) {
                size_t pos = (size_t)posl;
                size_t Ks = (size_t)K;
                out[pos]      = (float)ei[e];
                out[Ks + pos] = (float)ei[E + e];
#pragma unroll
                for (int rr = 0; rr < 14; ++rr)
                    out[(size_t)(2 + rr) * Ks + pos] = ew[(size_t)rr * E + e];
            }
        }
    }
}

// ---- launch ----------------------------------------------------------------

extern "C" void kernel_launch(void* const* d_in, const int* in_sizes, int n_in,
                              void* d_out, int out_size, void* d_ws, size_t ws_size,
                              hipStream_t stream) {
    const int*   ei = (const int*)d_in[1];
    const float* ew = (const float*)d_in[2];
    const float* W1 = (const float*)d_in[3];
    const float* b1 = (const float*)d_in[4];
    const float* W2 = (const float*)d_in[5];
    const float* b2 = (const float*)d_in[6];
    const float* rl = (const float*)d_in[7];

    long long E = (long long)in_sizes[2] / 14;
    int K = out_size / 16;
    int nchunks = (int)((E + CHUNK - 1) / CHUNK);
    int nblocks = (int)((E + BLOCK - 1) / BLOCK);

    // ws: s_arr E*4 | partial nblocks*8 | mm 8B | counts | offsets
    char* ws = (char*)d_ws;
    float*  s_arr   = (float*)ws;
    float2* partial = (float2*)(ws + (size_t)E * 4);
    float*  mm      = (float*)(ws + (size_t)E * 4 + (size_t)nblocks * 8);
    int*    counts  = (int*)(ws + (size_t)E * 4 + (size_t)nblocks * 8 + 8);
    int*    offsets = counts + nchunks;

    float* out = (float*)d_out;

    k_compute_s<<<nblocks, BLOCK, 0, stream>>>(ew, W1, b1, W2, b2, rl,
                                               s_arr, partial, E);
    k_minmax<<<1, 1024, 0, stream>>>(partial, nblocks, mm);
    k_count<<<nchunks, BLOCK, 0, stream>>>(s_arr, mm, counts, E);
    k_scan<<<1, 1024, 0, stream>>>(counts, offsets, nchunks);
    k_scatter<<<nchunks, BLOCK, 0, stream>>>(s_arr, mm, offsets, ei, ew, out, E, K);
}

// Round 16
// 173.944 us; speedup vs baseline: 1.4379x; 1.0621x over previous
//
#include <hip/hip_runtime.h>
#include <hip/hip_bf16.h>

// Edgedropping: per-edge MLP score -> sigmoid -> global min/max normalize ->
// mask -> stable stream compaction of edge_index (2 rows) + edge_weight (14 rows).
// Output buffer: float32.
// R16 = R15 (proven 184us x4) + ONE change: k_count caches ballot masks;
// k_scatter's pass 1 and pass-2 mask recompute are replaced by ballot loads.
// Pass-2 gather/write loop (the proven high-MLP structure) byte-identical.
// Evidence: R14 self-prefix=181 vs R11 self-prefix+ballots=170 -> ballots ~ -11us.

constexpr int BLOCK = 256;
constexpr int CHUNK = 4096;            // edges per count/scatter chunk
constexpr int ROUNDS = CHUNK / BLOCK;  // 16

__device__ __forceinline__ bool mask_of(float s, float vmin, float range) {
    float t = __fdiv_rn(__fsub_rn(s, vmin), range);
    float sn = __fadd_rn(__fmul_rn(t, 1.2f), -0.1f);
    return sn > 0.0f;
}

// ---- kernels ---------------------------------------------------------------

__global__ void k_compute_s(const float* __restrict__ ew,
                            const float* __restrict__ W1, const float* __restrict__ b1,
                            const float* __restrict__ W2, const float* __restrict__ b2,
                            const float* __restrict__ rl,
                            float* __restrict__ s_out,
                            float2* __restrict__ partial,
                            long long E) {
    __shared__ double sW1d[98], sW2d[7];
    __shared__ float sb1[7];
    __shared__ float sb2, srl;
    int tid = threadIdx.x;
    if (tid < 98) sW1d[tid] = (double)W1[tid];
    if (tid < 7) { sW2d[tid] = (double)W2[tid]; sb1[tid] = b1[tid]; }
    if (tid == 0) { sb2 = b2[0]; srl = rl[0]; }
    __syncthreads();

    long long e = (long long)blockIdx.x * BLOCK + tid;
    float lmin = __uint_as_float(0x7F800000u), lmax = 0.0f;

    if (e < E) {
        const float2* p2 = (const float2*)ew + e * 7;   // e*56 B, 8B-aligned
        float2 q0 = p2[0], q1 = p2[1], q2 = p2[2], q3 = p2[3],
               q4 = p2[4], q5 = p2[5], q6 = p2[6];
        float w[14] = {q0.x, q0.y, q1.x, q1.y, q2.x, q2.y, q3.x, q3.y,
                       q4.x, q4.y, q5.x, q5.y, q6.x, q6.y};

        // layer 1: 7 f64 dots, j-outer (per-k accumulation order matches R3 pass)
        double a0 = 0.0, a1 = 0.0, a2 = 0.0, a3 = 0.0, a4 = 0.0, a5 = 0.0, a6 = 0.0;
#pragma unroll
        for (int j = 0; j < 14; ++j) {
            double fd = (double)w[j];
            a0 += fd * sW1d[0 * 14 + j];
            a1 += fd * sW1d[1 * 14 + j];
            a2 += fd * sW1d[2 * 14 + j];
            a3 += fd * sW1d[3 * 14 + j];
            a4 += fd * sW1d[4 * 14 + j];
            a5 += fd * sW1d[5 * 14 + j];
            a6 += fd * sW1d[6 * 14 + j];
        }
        // layer 2 (same rounding points as passed versions)
        double acc2 = 0.0;
#define L2STEP(kk, ak) { float hp = __fadd_rn((float)(ak), sb1[kk]); \
                         hp = fmaxf(hp, 0.0f); \
                         acc2 += (double)hp * sW2d[kk]; }
        L2STEP(0, a0) L2STEP(1, a1) L2STEP(2, a2) L2STEP(3, a3)
        L2STEP(4, a4) L2STEP(5, a5) L2STEP(6, a6)
#undef L2STEP
        float raw = __fadd_rn((float)acc2, sb2);
        float z = __fdiv_rn(__fadd_rn(srl, raw), 0.05f);
        float s = __fdiv_rn(1.0f, __fadd_rn(1.0f, expf(-z)));
        s_out[e] = s;
        lmin = s;
        lmax = s;
    }
#pragma unroll
    for (int off = 32; off; off >>= 1) {
        lmin = fminf(lmin, __shfl_down(lmin, off));
        lmax = fmaxf(lmax, __shfl_down(lmax, off));
    }
    __shared__ float wmn[4], wmx[4];
    int lane = tid & 63, wid = tid >> 6;
    if (lane == 0) { wmn[wid] = lmin; wmx[wid] = lmax; }
    __syncthreads();
    if (tid == 0) {
        float m0 = wmn[0], M0 = wmx[0];
#pragma unroll
        for (int q = 1; q < 4; ++q) { m0 = fminf(m0, wmn[q]); M0 = fmaxf(M0, wmx[q]); }
        float2 pr; pr.x = m0; pr.y = M0;
        partial[blockIdx.x] = pr;
    }
}

// single block: reduce per-block partials -> mm[0]=vmin, mm[1]=vmax
__global__ void k_minmax(const float2* __restrict__ partial, int n,
                         float* __restrict__ mm) {
    int tid = threadIdx.x;
    float lmin = __uint_as_float(0x7F800000u), lmax = 0.0f;
    for (int i = tid; i < n; i += 1024) {
        float2 p = partial[i];
        lmin = fminf(lmin, p.x);
        lmax = fmaxf(lmax, p.y);
    }
#pragma unroll
    for (int off = 32; off; off >>= 1) {
        lmin = fminf(lmin, __shfl_down(lmin, off));
        lmax = fmaxf(lmax, __shfl_down(lmax, off));
    }
    __shared__ float wmn[16], wmx[16];
    int lane = tid & 63, wid = tid >> 6;
    if (lane == 0) { wmn[wid] = lmin; wmx[wid] = lmax; }
    __syncthreads();
    if (tid == 0) {
        float m = wmn[0], M = wmx[0];
#pragma unroll
        for (int q = 1; q < 16; ++q) { m = fminf(m, wmn[q]); M = fmaxf(M, wmx[q]); }
        mm[0] = m; mm[1] = M;
    }
}

// count + cache ballot masks (64 u64 per chunk)
__global__ void k_count(const float* __restrict__ s_arr,
                        const float* __restrict__ mm,
                        int* __restrict__ counts,
                        unsigned long long* __restrict__ ballots,
                        long long E) {
    int chunk = blockIdx.x;
    long long base = (long long)chunk * CHUNK;
    float vmin = mm[0];
    float range = __fsub_rn(mm[1], vmin);
    int tid = threadIdx.x, lane = tid & 63, wid = tid >> 6;
    int cnt = 0;
#pragma unroll
    for (int r = 0; r < ROUNDS; ++r) {
        long long e = base + r * BLOCK + tid;
        bool m = (e < E) && mask_of(s_arr[e], vmin, range);
        unsigned long long bal = __ballot(m);
        if (lane == 0) ballots[(size_t)chunk * 64 + r * 4 + wid] = bal;
        cnt += m ? 1 : 0;
    }
#pragma unroll
    for (int off = 32; off; off >>= 1) cnt += __shfl_down(cnt, off);
    __shared__ int wc[4];
    if (lane == 0) wc[wid] = cnt;
    __syncthreads();
    if (tid == 0) counts[chunk] = wc[0] + wc[1] + wc[2] + wc[3];
}

// single block, 1024 threads, LDS Hillis-Steele; requires nchunks <= 1024
__global__ void k_scan(const int* __restrict__ counts, int* __restrict__ offsets,
                       int nchunks) {
    __shared__ int tmp[1024];
    int tid = threadIdx.x;
    int v = (tid < nchunks) ? counts[tid] : 0;
    tmp[tid] = v;
    for (int off = 1; off < 1024; off <<= 1) {
        __syncthreads();
        int y = (tid >= off) ? tmp[tid - off] : 0;
        __syncthreads();
        tmp[tid] += y;
    }
    if (tid < nchunks) offsets[tid] = tmp[tid] - v;   // exclusive prefix
}

__global__ void k_scatter(const int* __restrict__ offsets,
                          const unsigned long long* __restrict__ ballots,
                          const int* __restrict__ ei,
                          const float* __restrict__ ew,
                          float* __restrict__ out,
                          long long E, int K) {
    int chunk = blockIdx.x;
    long long base = (long long)chunk * CHUNK;
    int tid = threadIdx.x, lane = tid & 63, wid = tid >> 6;

    __shared__ unsigned long long sbal[64];   // [round*4 + wave]
    __shared__ int off_rw[64];

    // load cached ballots; wave 0 scans popcounts in-register (own values, no barrier)
    if (tid < 64) {
        unsigned long long mybal = ballots[(size_t)chunk * 64 + tid];
        sbal[tid] = mybal;
        int v = (int)__popcll(mybal);
        int x = v;
#pragma unroll
        for (int off = 1; off < 64; off <<= 1) {
            int y = __shfl_up(x, off);
            if (lane >= off) x += y;
        }
        off_rw[tid] = x - v;   // exclusive
    }
    __syncthreads();

    int chunk_base = offsets[chunk];
    unsigned long long lt = (lane == 0) ? 0ull : ((1ull << lane) - 1ull);

    // pass 2: write (gather/write body byte-identical to R13/R15)
    for (int r = 0; r < ROUNDS; ++r) {
        unsigned long long bal = sbal[r * 4 + wid];
        bool m = (bal >> lane) & 1ULL;
        int myrank = __popcll(bal & lt);
        if (m) {
            long long e = base + r * BLOCK + tid;
            long long posl = (long long)chunk_base + off_rw[r * 4 + wid] + myrank;
            if (posl >= 0 && posl < (long long)K) {
                size_t pos = (size_t)posl;
                size_t Ks = (size_t)K;
                out[pos]      = (float)ei[e];
                out[Ks + pos] = (float)ei[E + e];
#pragma unroll
                for (int rr = 0; rr < 14; ++rr)
                    out[(size_t)(2 + rr) * Ks + pos] = ew[(size_t)rr * E + e];
            }
        }
    }
}

// ---- launch ----------------------------------------------------------------

extern "C" void kernel_launch(void* const* d_in, const int* in_sizes, int n_in,
                              void* d_out, int out_size, void* d_ws, size_t ws_size,
                              hipStream_t stream) {
    const int*   ei = (const int*)d_in[1];
    const float* ew = (const float*)d_in[2];
    const float* W1 = (const float*)d_in[3];
    const float* b1 = (const float*)d_in[4];
    const float* W2 = (const float*)d_in[5];
    const float* b2 = (const float*)d_in[6];
    const float* rl = (const float*)d_in[7];

    long long E = (long long)in_sizes[2] / 14;
    int K = out_size / 16;
    int nchunks = (int)((E + CHUNK - 1) / CHUNK);
    int nblocks = (int)((E + BLOCK - 1) / BLOCK);

    // ws: s_arr E*4 | partial nblocks*8 | mm 8B | counts nchunks*4 | offsets nchunks*4 | ballots nchunks*64*8
    char* ws = (char*)d_ws;
    float*  s_arr   = (float*)ws;
    size_t o1 = (size_t)E * 4;
    float2* partial = (float2*)(ws + o1);
    size_t o2 = o1 + (size_t)nblocks * 8;
    float*  mm      = (float*)(ws + o2);
    size_t o3 = o2 + 8;
    int*    counts  = (int*)(ws + o3);
    size_t o4 = o3 + (size_t)nchunks * 4;
    int*    offsets = (int*)(ws + o4);
    size_t o5 = (o4 + (size_t)nchunks * 4 + 7) & ~(size_t)7;
    unsigned long long* ballots = (unsigned long long*)(ws + o5);

    float* out = (float*)d_out;

    k_compute_s<<<nblocks, BLOCK, 0, stream>>>(ew, W1, b1, W2, b2, rl,
                                               s_arr, partial, E);
    k_minmax<<<1, 1024, 0, stream>>>(partial, nblocks, mm);
    k_count<<<nchunks, BLOCK, 0, stream>>>(s_arr, mm, counts, ballots, E);
    k_scan<<<1, 1024, 0, stream>>>(counts, offsets, nchunks);
    k_scatter<<<nchunks, BLOCK, 0, stream>>>(offsets, ballots, ei, ew, out, E, K);
}